// Round 6
// baseline (168.897 us; speedup 1.0000x reference)
//
#include <hip/hip_runtime.h>

// Batched Kalman filter update: B=262144 independent 8-state / 4-obs updates.
// One thread per batch. P input staged via global_load_lds (linear LDS dest,
// inverse-swizzled per-lane global source, swizzled ds_read); output staged
// through the same wave-private 576-float4 LDS region in two 32-lane halves.
// All phase ordering via __syncthreads (uniform, drains vmcnt+lgkmcnt).
// 36864 B LDS/block -> 4 blocks/CU -> 16 waves/CU (whole grid resident).
constexpr int B_N = 262144;
constexpr int DX  = 8;
constexpr int DZ  = 4;

typedef __attribute__((address_space(1))) const void GA1;
typedef __attribute__((address_space(3))) void LA3;

__device__ __forceinline__ void gll16(const void* g, void* l) {
    __builtin_amdgcn_global_load_lds((GA1*)g, (LA3*)l, 16, 0, 0);
}
// float4-index swizzle: involution, flips low 3 bits by bits[4:6] -> stays in
// any aligned 64-f4 span (coalescing preserved) and spreads LDS bank groups.
__device__ __forceinline__ int swz(int i) { return i ^ ((i >> 4) & 7); }

__global__ __launch_bounds__(256, 4) void kalman_update(
    const float* __restrict__ x_in,   // [B, 8, 1]
    const float* __restrict__ z_in,   // [B, 4, 1]
    const float* __restrict__ P_in,   // [B, 8, 8]
    const float* __restrict__ H_in,   // [4, 8]   (uniform)
    const float* __restrict__ R_in,   // [4, 4]   (uniform)
    float* __restrict__ out)          // [B, 9, 8] = cat(x_new^T, P_new)
{
    __shared__ float4 lds[4 * 576];   // 9 KiB per wave, 36 KiB per block

    const int wave = threadIdx.x >> 6;
    const int lane = threadIdx.x & 63;
    const int m    = lane & 31;
    float4* const slice = lds + wave * 576;

    const int wbatch = blockIdx.x * 256 + wave * 64;  // wave's first batch
    const int b      = wbatch + lane;

    const float4* Pg = reinterpret_cast<const float4*>(P_in) + (size_t)wbatch * 16;

    // ---- stage P half 0 (batches wbatch..+31 = 512 f4), direct to LDS ----
    // LDS slot d holds global f4 Pg[swz(d)]; reading slot swz(r) yields Pg[r].
#pragma unroll
    for (int k = 0; k < 8; ++k)
        gll16(&Pg[swz(64 * k + lane)], &slice[64 * k]);

    // ---- x (stride-32B per-lane), z (coalesced) direct loads ----
    float x[DX], y[DZ];
    {
        const float4* xp = reinterpret_cast<const float4*>(x_in) + (size_t)b * 2;
        const float4 a = xp[0], c = xp[1];
        x[0] = a.x; x[1] = a.y; x[2] = a.z; x[3] = a.w;
        x[4] = c.x; x[5] = c.y; x[6] = c.z; x[7] = c.w;
        const float4 zz = reinterpret_cast<const float4*>(z_in)[b];
        y[0] = zz.x; y[1] = zz.y; y[2] = zz.z; y[3] = zz.w;
    }

    // ---- uniform small matrices (uniform address -> scalar loads) ----
    float H[DZ][DX];
#pragma unroll
    for (int i = 0; i < DZ * DX; ++i) H[i / DX][i % DX] = H_in[i];
    float R[DZ][DZ];
#pragma unroll
    for (int i = 0; i < DZ * DZ; ++i) R[i / DZ][i % DZ] = R_in[i];

    float P[DX][DX];
    auto readP = [&]() {
#pragma unroll
        for (int j = 0; j < 16; ++j) {
            const float4 v = slice[swz(16 * m + j)];
            const int r = j >> 1, c = (j & 1) * 4;
            P[r][c + 0] = v.x; P[r][c + 1] = v.y; P[r][c + 2] = v.z; P[r][c + 3] = v.w;
        }
    };

    __syncthreads();                  // half-0 staged into LDS
    if (lane < 32) readP();
    __syncthreads();                  // half-0 LDS reads complete (WAR guard)

    // stage P half 1 into the same region
#pragma unroll
    for (int k = 0; k < 8; ++k)
        gll16(&Pg[512 + swz(64 * k + lane)], &slice[64 * k]);

    // ---- y = z - H x (VALU; overlaps half-1 DMA latency) ----
#pragma unroll
    for (int zi = 0; zi < DZ; ++zi) {
        float acc = 0.f;
#pragma unroll
        for (int k = 0; k < DX; ++k) acc += H[zi][k] * x[k];
        y[zi] -= acc;
    }

    __syncthreads();                  // half-1 staged into LDS
    if (lane >= 32) readP();

    // ---- PHT = P H^T [8][4] ----
    float PHT[DX][DZ];
#pragma unroll
    for (int i = 0; i < DX; ++i)
#pragma unroll
        for (int j = 0; j < DZ; ++j) {
            float acc = 0.f;
#pragma unroll
            for (int k = 0; k < DX; ++k) acc += P[i][k] * H[j][k];
            PHT[i][j] = acc;
        }

    // ---- S = H PHT + R [4][4] ----
    float S[DZ][DZ];
#pragma unroll
    for (int a = 0; a < DZ; ++a)
#pragma unroll
        for (int c = 0; c < DZ; ++c) {
            float acc = R[a][c];
#pragma unroll
            for (int k = 0; k < DX; ++k) acc += H[a][k] * PHT[k][c];
            S[a][c] = acc;
        }

    // ---- SI = inv(S) via adjugate (S SPD, well conditioned: R = I) ----
    float SI[DZ][DZ];
    {
        const float A2323 = S[2][2]*S[3][3] - S[2][3]*S[3][2];
        const float A1323 = S[2][1]*S[3][3] - S[2][3]*S[3][1];
        const float A1223 = S[2][1]*S[3][2] - S[2][2]*S[3][1];
        const float A0323 = S[2][0]*S[3][3] - S[2][3]*S[3][0];
        const float A0223 = S[2][0]*S[3][2] - S[2][2]*S[3][0];
        const float A0123 = S[2][0]*S[3][1] - S[2][1]*S[3][0];
        const float A2313 = S[1][2]*S[3][3] - S[1][3]*S[3][2];
        const float A1313 = S[1][1]*S[3][3] - S[1][3]*S[3][1];
        const float A1213 = S[1][1]*S[3][2] - S[1][2]*S[3][1];
        const float A2312 = S[1][2]*S[2][3] - S[1][3]*S[2][2];
        const float A1312 = S[1][1]*S[2][3] - S[1][3]*S[2][1];
        const float A1212 = S[1][1]*S[2][2] - S[1][2]*S[2][1];
        const float A0313 = S[1][0]*S[3][3] - S[1][3]*S[3][0];
        const float A0213 = S[1][0]*S[3][2] - S[1][2]*S[3][0];
        const float A0312 = S[1][0]*S[2][3] - S[1][3]*S[2][0];
        const float A0212 = S[1][0]*S[2][2] - S[1][2]*S[2][0];
        const float A0113 = S[1][0]*S[3][1] - S[1][1]*S[3][0];
        const float A0112 = S[1][0]*S[2][1] - S[1][1]*S[2][0];

        float det = S[0][0] * (S[1][1]*A2323 - S[1][2]*A1323 + S[1][3]*A1223)
                  - S[0][1] * (S[1][0]*A2323 - S[1][2]*A0323 + S[1][3]*A0223)
                  + S[0][2] * (S[1][0]*A1323 - S[1][1]*A0323 + S[1][3]*A0123)
                  - S[0][3] * (S[1][0]*A1223 - S[1][1]*A0223 + S[1][2]*A0123);
        const float id = 1.0f / det;

        SI[0][0] = id *  (S[1][1]*A2323 - S[1][2]*A1323 + S[1][3]*A1223);
        SI[0][1] = id * -(S[0][1]*A2323 - S[0][2]*A1323 + S[0][3]*A1223);
        SI[0][2] = id *  (S[0][1]*A2313 - S[0][2]*A1313 + S[0][3]*A1213);
        SI[0][3] = id * -(S[0][1]*A2312 - S[0][2]*A1312 + S[0][3]*A1212);
        SI[1][0] = id * -(S[1][0]*A2323 - S[1][2]*A0323 + S[1][3]*A0223);
        SI[1][1] = id *  (S[0][0]*A2323 - S[0][2]*A0323 + S[0][3]*A0223);
        SI[1][2] = id * -(S[0][0]*A2313 - S[0][2]*A0313 + S[0][3]*A0213);
        SI[1][3] = id *  (S[0][0]*A2312 - S[0][2]*A0312 + S[0][3]*A0212);
        SI[2][0] = id *  (S[1][0]*A1323 - S[1][1]*A0323 + S[1][3]*A0123);
        SI[2][1] = id * -(S[0][0]*A1323 - S[0][1]*A0323 + S[0][3]*A0123);
        SI[2][2] = id *  (S[0][0]*A1313 - S[0][1]*A0313 + S[0][3]*A0113);
        SI[2][3] = id * -(S[0][0]*A1312 - S[0][1]*A0312 + S[0][3]*A0112);
        SI[3][0] = id * -(S[1][0]*A1223 - S[1][1]*A0223 + S[1][2]*A0123);
        SI[3][1] = id *  (S[0][0]*A1223 - S[0][1]*A0223 + S[0][2]*A0123);
        SI[3][2] = id * -(S[0][0]*A1213 - S[0][1]*A0213 + S[0][2]*A0113);
        SI[3][3] = id *  (S[0][0]*A1212 - S[0][1]*A0212 + S[0][2]*A0112);
    }

    // ---- K = PHT * SI [8][4] ----
    float K[DX][DZ];
#pragma unroll
    for (int i = 0; i < DX; ++i)
#pragma unroll
        for (int j = 0; j < DZ; ++j) {
            float acc = 0.f;
#pragma unroll
            for (int w = 0; w < DZ; ++w) acc += PHT[i][w] * SI[w][j];
            K[i][j] = acc;
        }

    // ---- x_new = x + K y ----
    float xn[DX];
#pragma unroll
    for (int i = 0; i < DX; ++i) {
        float acc = x[i];
#pragma unroll
        for (int zi = 0; zi < DZ; ++zi) acc += K[i][zi] * y[zi];
        xn[i] = acc;
    }

    // ---- B = (I - K H) P = P - K (H P); H P = PHT^T since P symmetric ----
#pragma unroll
    for (int i = 0; i < DX; ++i)
#pragma unroll
        for (int j = 0; j < DX; ++j) {
            float acc = P[i][j];
#pragma unroll
            for (int zi = 0; zi < DZ; ++zi) acc -= K[i][zi] * PHT[j][zi];
            P[i][j] = acc;
        }

    // ---- E = K R - B H^T [8][4] ----
    float E[DX][DZ];
#pragma unroll
    for (int i = 0; i < DX; ++i)
#pragma unroll
        for (int zi = 0; zi < DZ; ++zi) {
            float acc = 0.f;
#pragma unroll
            for (int w = 0; w < DZ; ++w) acc += K[i][w] * R[w][zi];
#pragma unroll
            for (int k = 0; k < DX; ++k) acc -= P[i][k] * H[zi][k];
            E[i][zi] = acc;
        }

    // ---- P_new = B + E K^T (in-place on P) ----
#pragma unroll
    for (int i = 0; i < DX; ++i)
#pragma unroll
        for (int j = 0; j < DX; ++j) {
            float acc = P[i][j];
#pragma unroll
            for (int zi = 0; zi < DZ; ++zi) acc += E[i][zi] * K[j][zi];
            P[i][j] = acc;
        }

    // ---- output staging in two 32-lane halves through slice[0,576) ----
    auto writeOut = [&]() {
        slice[swz(18 * m + 0)] = make_float4(xn[0], xn[1], xn[2], xn[3]);
        slice[swz(18 * m + 1)] = make_float4(xn[4], xn[5], xn[6], xn[7]);
#pragma unroll
        for (int i = 0; i < DX; ++i) {
            slice[swz(18 * m + 2 + 2 * i)]     = make_float4(P[i][0], P[i][1], P[i][2], P[i][3]);
            slice[swz(18 * m + 2 + 2 * i + 1)] = make_float4(P[i][4], P[i][5], P[i][6], P[i][7]);
        }
    };
    float4* Og = reinterpret_cast<float4*>(out) + (size_t)wbatch * 18;

    if (lane < 32) writeOut();        // batches wbatch..+31 (576 f4)
    __syncthreads();                  // writes visible; prior reads drained
#pragma unroll
    for (int k = 0; k < 9; ++k) {
        const int d = 64 * k + lane;
        Og[d] = slice[swz(d)];
    }
    __syncthreads();                  // flush-A LDS reads complete (WAR guard)
    if (lane >= 32) writeOut();       // batches wbatch+32..+63
    __syncthreads();
#pragma unroll
    for (int k = 0; k < 9; ++k) {
        const int d = 64 * k + lane;
        Og[576 + d] = slice[swz(d)];
    }
}

extern "C" void kernel_launch(void* const* d_in, const int* in_sizes, int n_in,
                              void* d_out, int out_size, void* d_ws, size_t ws_size,
                              hipStream_t stream) {
    const float* x = (const float*)d_in[0];
    const float* z = (const float*)d_in[1];
    const float* P = (const float*)d_in[2];
    const float* H = (const float*)d_in[3];
    const float* R = (const float*)d_in[4];
    float* out = (float*)d_out;

    dim3 grid(B_N / 256), block(256);
    hipLaunchKernelGGL(kalman_update, grid, block, 0, stream, x, z, P, H, R, out);
}

// Round 8
// 147.287 us; speedup vs baseline: 1.1467x; 1.1467x over previous
//
#include <hip/hip_runtime.h>

// Batched Kalman filter update: B=262144 independent 8-state / 4-obs updates.
// One thread per batch. P input staged via global_load_lds (linear LDS dest,
// inverse-swizzled per-lane global source, swizzled ds_read); output staged
// through the same wave-private 576-float4 LDS region in two 32-lane halves.
// All phase ordering via __syncthreads (uniform, drains vmcnt+lgkmcnt).
// 36864 B LDS/block -> 4 blocks/CU -> 16 waves/CU (whole grid resident).
// NOTE: no min-waves arg in __launch_bounds__ — (256,4) forced VGPR=64 and
// spilled the register-resident working set to scratch (R6: WRITE_SIZE 2x).
constexpr int B_N = 262144;
constexpr int DX  = 8;
constexpr int DZ  = 4;

typedef __attribute__((address_space(1))) const void GA1;
typedef __attribute__((address_space(3))) void LA3;

__device__ __forceinline__ void gll16(const void* g, void* l) {
    __builtin_amdgcn_global_load_lds((GA1*)g, (LA3*)l, 16, 0, 0);
}
// float4-index swizzle: involution, flips low 3 bits by bits[4:6] -> stays in
// any aligned 64-f4 span (coalescing preserved) and spreads LDS bank groups.
__device__ __forceinline__ int swz(int i) { return i ^ ((i >> 4) & 7); }

__global__ __launch_bounds__(256) void kalman_update(
    const float* __restrict__ x_in,   // [B, 8, 1]
    const float* __restrict__ z_in,   // [B, 4, 1]
    const float* __restrict__ P_in,   // [B, 8, 8]
    const float* __restrict__ H_in,   // [4, 8]   (uniform)
    const float* __restrict__ R_in,   // [4, 4]   (uniform)
    float* __restrict__ out)          // [B, 9, 8] = cat(x_new^T, P_new)
{
    __shared__ float4 lds[4 * 576];   // 9 KiB per wave, 36 KiB per block

    const int wave = threadIdx.x >> 6;
    const int lane = threadIdx.x & 63;
    const int m    = lane & 31;
    float4* const slice = lds + wave * 576;

    const int wbatch = blockIdx.x * 256 + wave * 64;  // wave's first batch
    const int b      = wbatch + lane;

    const float4* Pg = reinterpret_cast<const float4*>(P_in) + (size_t)wbatch * 16;

    // ---- stage P half 0 (batches wbatch..+31 = 512 f4), direct to LDS ----
    // LDS slot d holds global f4 Pg[swz(d)]; reading slot swz(r) yields Pg[r].
#pragma unroll
    for (int k = 0; k < 8; ++k)
        gll16(&Pg[swz(64 * k + lane)], &slice[64 * k]);

    // ---- x (stride-32B per-lane), z (coalesced) direct loads ----
    float x[DX], y[DZ];
    {
        const float4* xp = reinterpret_cast<const float4*>(x_in) + (size_t)b * 2;
        const float4 a = xp[0], c = xp[1];
        x[0] = a.x; x[1] = a.y; x[2] = a.z; x[3] = a.w;
        x[4] = c.x; x[5] = c.y; x[6] = c.z; x[7] = c.w;
        const float4 zz = reinterpret_cast<const float4*>(z_in)[b];
        y[0] = zz.x; y[1] = zz.y; y[2] = zz.z; y[3] = zz.w;
    }

    // ---- uniform small matrices (uniform address -> scalar loads) ----
    float H[DZ][DX];
#pragma unroll
    for (int i = 0; i < DZ * DX; ++i) H[i / DX][i % DX] = H_in[i];
    float R[DZ][DZ];
#pragma unroll
    for (int i = 0; i < DZ * DZ; ++i) R[i / DZ][i % DZ] = R_in[i];

    float P[DX][DX];
    auto readP = [&]() {
#pragma unroll
        for (int j = 0; j < 16; ++j) {
            const float4 v = slice[swz(16 * m + j)];
            const int r = j >> 1, c = (j & 1) * 4;
            P[r][c + 0] = v.x; P[r][c + 1] = v.y; P[r][c + 2] = v.z; P[r][c + 3] = v.w;
        }
    };

    __syncthreads();                  // half-0 staged into LDS
    if (lane < 32) readP();
    __syncthreads();                  // half-0 LDS reads complete (WAR guard)

    // stage P half 1 into the same region
#pragma unroll
    for (int k = 0; k < 8; ++k)
        gll16(&Pg[512 + swz(64 * k + lane)], &slice[64 * k]);

    // ---- y = z - H x (VALU; overlaps half-1 DMA latency) ----
#pragma unroll
    for (int zi = 0; zi < DZ; ++zi) {
        float acc = 0.f;
#pragma unroll
        for (int k = 0; k < DX; ++k) acc += H[zi][k] * x[k];
        y[zi] -= acc;
    }

    __syncthreads();                  // half-1 staged into LDS
    if (lane >= 32) readP();

    // ---- PHT = P H^T [8][4] ----
    float PHT[DX][DZ];
#pragma unroll
    for (int i = 0; i < DX; ++i)
#pragma unroll
        for (int j = 0; j < DZ; ++j) {
            float acc = 0.f;
#pragma unroll
            for (int k = 0; k < DX; ++k) acc += P[i][k] * H[j][k];
            PHT[i][j] = acc;
        }

    // ---- S = H PHT + R [4][4] ----
    float S[DZ][DZ];
#pragma unroll
    for (int a = 0; a < DZ; ++a)
#pragma unroll
        for (int c = 0; c < DZ; ++c) {
            float acc = R[a][c];
#pragma unroll
            for (int k = 0; k < DX; ++k) acc += H[a][k] * PHT[k][c];
            S[a][c] = acc;
        }

    // ---- SI = inv(S) via adjugate (S SPD, well conditioned: R = I) ----
    float SI[DZ][DZ];
    {
        const float A2323 = S[2][2]*S[3][3] - S[2][3]*S[3][2];
        const float A1323 = S[2][1]*S[3][3] - S[2][3]*S[3][1];
        const float A1223 = S[2][1]*S[3][2] - S[2][2]*S[3][1];
        const float A0323 = S[2][0]*S[3][3] - S[2][3]*S[3][0];
        const float A0223 = S[2][0]*S[3][2] - S[2][2]*S[3][0];
        const float A0123 = S[2][0]*S[3][1] - S[2][1]*S[3][0];
        const float A2313 = S[1][2]*S[3][3] - S[1][3]*S[3][2];
        const float A1313 = S[1][1]*S[3][3] - S[1][3]*S[3][1];
        const float A1213 = S[1][1]*S[3][2] - S[1][2]*S[3][1];
        const float A2312 = S[1][2]*S[2][3] - S[1][3]*S[2][2];
        const float A1312 = S[1][1]*S[2][3] - S[1][3]*S[2][1];
        const float A1212 = S[1][1]*S[2][2] - S[1][2]*S[2][1];
        const float A0313 = S[1][0]*S[3][3] - S[1][3]*S[3][0];
        const float A0213 = S[1][0]*S[3][2] - S[1][2]*S[3][0];
        const float A0312 = S[1][0]*S[2][3] - S[1][3]*S[2][0];
        const float A0212 = S[1][0]*S[2][2] - S[1][2]*S[2][0];
        const float A0113 = S[1][0]*S[3][1] - S[1][1]*S[3][0];
        const float A0112 = S[1][0]*S[2][1] - S[1][1]*S[2][0];

        float det = S[0][0] * (S[1][1]*A2323 - S[1][2]*A1323 + S[1][3]*A1223)
                  - S[0][1] * (S[1][0]*A2323 - S[1][2]*A0323 + S[1][3]*A0223)
                  + S[0][2] * (S[1][0]*A1323 - S[1][1]*A0323 + S[1][3]*A0123)
                  - S[0][3] * (S[1][0]*A1223 - S[1][1]*A0223 + S[1][2]*A0123);
        const float id = 1.0f / det;

        SI[0][0] = id *  (S[1][1]*A2323 - S[1][2]*A1323 + S[1][3]*A1223);
        SI[0][1] = id * -(S[0][1]*A2323 - S[0][2]*A1323 + S[0][3]*A1223);
        SI[0][2] = id *  (S[0][1]*A2313 - S[0][2]*A1313 + S[0][3]*A1213);
        SI[0][3] = id * -(S[0][1]*A2312 - S[0][2]*A1312 + S[0][3]*A1212);
        SI[1][0] = id * -(S[1][0]*A2323 - S[1][2]*A0323 + S[1][3]*A0223);
        SI[1][1] = id *  (S[0][0]*A2323 - S[0][2]*A0323 + S[0][3]*A0223);
        SI[1][2] = id * -(S[0][0]*A2313 - S[0][2]*A0313 + S[0][3]*A0213);
        SI[1][3] = id *  (S[0][0]*A2312 - S[0][2]*A0312 + S[0][3]*A0212);
        SI[2][0] = id *  (S[1][0]*A1323 - S[1][1]*A0323 + S[1][3]*A0123);
        SI[2][1] = id * -(S[0][0]*A1323 - S[0][1]*A0323 + S[0][3]*A0123);
        SI[2][2] = id *  (S[0][0]*A1313 - S[0][1]*A0313 + S[0][3]*A0113);
        SI[2][3] = id * -(S[0][0]*A1312 - S[0][1]*A0312 + S[0][3]*A0112);
        SI[3][0] = id * -(S[1][0]*A1223 - S[1][1]*A0223 + S[1][2]*A0123);
        SI[3][1] = id *  (S[0][0]*A1223 - S[0][1]*A0223 + S[0][2]*A0123);
        SI[3][2] = id * -(S[0][0]*A1213 - S[0][1]*A0213 + S[0][2]*A0113);
        SI[3][3] = id *  (S[0][0]*A1212 - S[0][1]*A0212 + S[0][2]*A0112);
    }

    // ---- K = PHT * SI [8][4] ----
    float K[DX][DZ];
#pragma unroll
    for (int i = 0; i < DX; ++i)
#pragma unroll
        for (int j = 0; j < DZ; ++j) {
            float acc = 0.f;
#pragma unroll
            for (int w = 0; w < DZ; ++w) acc += PHT[i][w] * SI[w][j];
            K[i][j] = acc;
        }

    // ---- x_new = x + K y ----
    float xn[DX];
#pragma unroll
    for (int i = 0; i < DX; ++i) {
        float acc = x[i];
#pragma unroll
        for (int zi = 0; zi < DZ; ++zi) acc += K[i][zi] * y[zi];
        xn[i] = acc;
    }

    // ---- B = (I - K H) P = P - K (H P); H P = PHT^T since P symmetric ----
#pragma unroll
    for (int i = 0; i < DX; ++i)
#pragma unroll
        for (int j = 0; j < DX; ++j) {
            float acc = P[i][j];
#pragma unroll
            for (int zi = 0; zi < DZ; ++zi) acc -= K[i][zi] * PHT[j][zi];
            P[i][j] = acc;
        }

    // ---- E = K R - B H^T [8][4] ----
    float E[DX][DZ];
#pragma unroll
    for (int i = 0; i < DX; ++i)
#pragma unroll
        for (int zi = 0; zi < DZ; ++zi) {
            float acc = 0.f;
#pragma unroll
            for (int w = 0; w < DZ; ++w) acc += K[i][w] * R[w][zi];
#pragma unroll
            for (int k = 0; k < DX; ++k) acc -= P[i][k] * H[zi][k];
            E[i][zi] = acc;
        }

    // ---- P_new = B + E K^T (in-place on P) ----
#pragma unroll
    for (int i = 0; i < DX; ++i)
#pragma unroll
        for (int j = 0; j < DX; ++j) {
            float acc = P[i][j];
#pragma unroll
            for (int zi = 0; zi < DZ; ++zi) acc += E[i][zi] * K[j][zi];
            P[i][j] = acc;
        }

    // ---- output staging in two 32-lane halves through slice[0,576) ----
    auto writeOut = [&]() {
        slice[swz(18 * m + 0)] = make_float4(xn[0], xn[1], xn[2], xn[3]);
        slice[swz(18 * m + 1)] = make_float4(xn[4], xn[5], xn[6], xn[7]);
#pragma unroll
        for (int i = 0; i < DX; ++i) {
            slice[swz(18 * m + 2 + 2 * i)]     = make_float4(P[i][0], P[i][1], P[i][2], P[i][3]);
            slice[swz(18 * m + 2 + 2 * i + 1)] = make_float4(P[i][4], P[i][5], P[i][6], P[i][7]);
        }
    };
    float4* Og = reinterpret_cast<float4*>(out) + (size_t)wbatch * 18;

    if (lane < 32) writeOut();        // batches wbatch..+31 (576 f4)
    __syncthreads();                  // writes visible; prior reads drained
#pragma unroll
    for (int k = 0; k < 9; ++k) {
        const int d = 64 * k + lane;
        Og[d] = slice[swz(d)];
    }
    __syncthreads();                  // flush-A LDS reads complete (WAR guard)
    if (lane >= 32) writeOut();       // batches wbatch+32..+63
    __syncthreads();
#pragma unroll
    for (int k = 0; k < 9; ++k) {
        const int d = 64 * k + lane;
        Og[576 + d] = slice[swz(d)];
    }
}

extern "C" void kernel_launch(void* const* d_in, const int* in_sizes, int n_in,
                              void* d_out, int out_size, void* d_ws, size_t ws_size,
                              hipStream_t stream) {
    const float* x = (const float*)d_in[0];
    const float* z = (const float*)d_in[1];
    const float* P = (const float*)d_in[2];
    const float* H = (const float*)d_in[3];
    const float* R = (const float*)d_in[4];
    float* out = (float*)d_out;

    dim3 grid(B_N / 256), block(256);
    hipLaunchKernelGGL(kalman_update, grid, block, 0, stream, x, z, P, H, R, out);
}